// Round 14
// baseline (124.999 us; speedup 1.0000x reference)
//
#include <hip/hip_runtime.h>

typedef _Float16 f16x8 __attribute__((ext_vector_type(8)));
typedef _Float16 f16x2 __attribute__((ext_vector_type(2)));
typedef float    f32x4 __attribute__((ext_vector_type(4)));
typedef float    f32x2 __attribute__((ext_vector_type(2)));

#define N_ROWS 8192
#define DIM 64
#define EPS 1e-8f
#define LOG2E 1.4426950408889634f
#define SHIFT 64.0f                      // exp terms scaled by 2^64
#define SHIFT_LN 44.361419555836499802f  // 64 * ln(2)
#define TILE_I 256                       // i-panel (4 waves x 64 rows, mt=4)
#define NBI (N_ROWS / TILE_I)            // 32 panels
#define TB 512                           // EXACTLY one block per CU slot
#define MAXC 17                          // max j-chunks (16 rows each) per block

// last-block counter for fused finalization (zeroed by snn_prep each launch)
__device__ unsigned int g_ctr;

// ws: top[8192] | bot[8192] | sq[8192] (f32) | xh[8192*64] | xl[8192*64] (f16)

// fused prep: zero top/bot/out/ctr + f16 split + row norms.
// G13: float2 loads (8B/lane), packed f16x2 stores; 2 rows per wave.
__global__ void snn_prep(const float* __restrict__ x, _Float16* __restrict__ xh,
                         _Float16* __restrict__ xl, float* __restrict__ sq,
                         float* __restrict__ top, float* __restrict__ bot,
                         float* __restrict__ out) {
    const int gt = blockIdx.x * 256 + threadIdx.x;
    if (gt < N_ROWS) { top[gt] = 0.0f; bot[gt] = 0.0f; }
    if (gt == 0) { out[0] = 0.0f; g_ctr = 0u; }
    const int lane = threadIdx.x & 63;
    const int row = gt >> 5;                 // 2 rows per wave
    const int cp  = (lane & 31) * 2;         // this lane's column pair
    f32x2 v = *(const f32x2*)(x + row * DIM + cp);
    _Float16 h0 = (_Float16)v[0], h1 = (_Float16)v[1];
    _Float16 l0 = (_Float16)(v[0] - (float)h0);
    _Float16 l1 = (_Float16)(v[1] - (float)h1);
    *(f16x2*)(xh + row * DIM + cp) = (f16x2){h0, h1};
    *(f16x2*)(xl + row * DIM + cp) = (f16x2){l0, l1};
    float s = v[0] * v[0] + v[1] * v[1];
    #pragma unroll
    for (int off = 16; off > 0; off >>= 1) s += __shfl_xor(s, off, 64);
    if ((lane & 31) == 0) sq[row] = s;
}

// Symmetric triangular pass — R13 body VERBATIM (best: total 94.3us), plus
// fused last-block finalization (saves the snn_final dispatch + gap ~2.5us).
// Final state of the 14-round map:
//  - R8 partition: 512 uniform blocks (16-17 chunks) -> ONE scheduling round
//  - 2-wide iterations: widest body fitting the empirical 128-VGPR wall
//    (R12: 4-wide -> spill; R3/R9 same law)
//  - col-side partials via per-lane f32x2 LDS stores (R13, neutral-to-+)
//  - measured nulls: TLP (R10), LDS B-staging (R6), SW prefetch (R3/R5)
__global__ __launch_bounds__(256, 2) void snn_mfma(
    const _Float16* __restrict__ xh, const _Float16* __restrict__ xl,
    const float* __restrict__ sq, const int* __restrict__ y,
    const float* __restrict__ w,
    float* __restrict__ top, float* __restrict__ bot,
    float* __restrict__ out)
{
    __shared__ float s_sqj[MAXC * 16];
    __shared__ int   s_yj[MAXC * 16];
    __shared__ f32x2 s_j[4][4][MAXC * 16];   // [wave][kq][col] {top,bot} partials
    __shared__ bool  s_last;
    __shared__ float s_red[4];

    // ---- decode bid -> (panel bi, chunk range [c0, c0+len)) — R8 verbatim ----
    const int bid = blockIdx.x;
    int bi = 0, kk = 0, cum = 0;
    for (int p = 0; p < NBI; p++) {
        int nb = (p < 16) ? p + 1 : p;          // blocks in panel p
        if (bid < cum + nb) { bi = p; kk = bid - cum; break; }
        cum += nb;
    }
    int c0, len;
    if (bi < 16)      { c0 = 16 * kk;              len = 16; }
    else if (kk < 16) { c0 = 17 * kk;              len = 17; }
    else              { c0 = 272 + 16 * (kk - 16); len = 16; }
    const int ndch = min(max(16 * bi - c0, 0), len);  // leading non-diag chunks
    const int I0 = bi * TILE_I;

    const int tid = threadIdx.x, wv = tid >> 6, lane = tid & 63;
    const int mrow = lane & 15, kq = lane >> 4;

    for (int t = tid; t < len * 16; t += 256) {
        s_sqj[t] = sq[c0 * 16 + t];
        s_yj[t]  = y[c0 * 16 + t];
    }
    __syncthreads();

    const int iw = I0 + wv * 64;   // this wave's first i-row

    // A fragments resident for the block lifetime (64 VGPRs)
    f16x8 ah[4][2], al[4][2];
    #pragma unroll
    for (int mt = 0; mt < 4; mt++)
        #pragma unroll
        for (int kc = 0; kc < 2; kc++) {
            int a = (iw + mt * 16 + mrow) * DIM + kc * 32 + kq * 8;
            ah[mt][kc] = *(const f16x8*)(xh + a);
            al[mt][kc] = *(const f16x8*)(xl + a);
        }

    // per-slot row metadata: i = iw + mt*16 + kq*4 + rr ; labels packed 4/VGPR
    float sqi[4][4]; int ypack[4];
    #pragma unroll
    for (int mt = 0; mt < 4; mt++) {
        int yp = 0;
        #pragma unroll
        for (int rr = 0; rr < 4; rr++) {
            int i = iw + mt * 16 + kq * 4 + rr;
            sqi[mt][rr] = sq[i];
            yp |= (y[i] & 255) << (8 * rr);
        }
        ypack[mt] = yp;
    }

    float ts[4][4], bs[4][4];
    #pragma unroll
    for (int mt = 0; mt < 4; mt++)
        #pragma unroll
        for (int rr = 0; rr < 4; rr++) { ts[mt][rr] = 0.0f; bs[mt][rr] = 0.0f; }

    const float c1 = -w[0] * LOG2E;
    f32x4 acc[4];

// declare + issue loads for one chunk (suffix N), chunk index NTL
#define DECL_LOAD(N, NTL)                                                        \
    const int jr##N = (c0 + (NTL)) * 16 + mrow;                                  \
    const int boff##N = jr##N * DIM + kq * 8;                                    \
    f16x8 cbh0##N = *(const f16x8*)(xh + boff##N);                               \
    f16x8 cbh1##N = *(const f16x8*)(xh + boff##N + 32);                          \
    f16x8 cbl0##N = *(const f16x8*)(xl + boff##N);                               \
    f16x8 cbl1##N = *(const f16x8*)(xl + boff##N + 32);                          \
    const float sqj##N = s_sqj[(NTL) * 16 + mrow];                               \
    const int   yj##N  = s_yj[(NTL) * 16 + mrow];

#define DO_MFMA(N)                                                               \
    _Pragma("unroll")                                                            \
    for (int mt = 0; mt < 4; mt++) acc[mt] = (f32x4){0.f, 0.f, 0.f, 0.f};        \
    _Pragma("unroll")                                                            \
    for (int mt = 0; mt < 4; mt++)                                               \
        acc[mt] = __builtin_amdgcn_mfma_f32_16x16x32_f16(ah[mt][0], cbh0##N, acc[mt], 0, 0, 0); \
    _Pragma("unroll")                                                            \
    for (int mt = 0; mt < 4; mt++)                                               \
        acc[mt] = __builtin_amdgcn_mfma_f32_16x16x32_f16(ah[mt][1], cbh1##N, acc[mt], 0, 0, 0); \
    _Pragma("unroll")                                                            \
    for (int mt = 0; mt < 4; mt++)                                               \
        acc[mt] = __builtin_amdgcn_mfma_f32_16x16x32_f16(ah[mt][0], cbl0##N, acc[mt], 0, 0, 0); \
    _Pragma("unroll")                                                            \
    for (int mt = 0; mt < 4; mt++)                                               \
        acc[mt] = __builtin_amdgcn_mfma_f32_16x16x32_f16(ah[mt][1], cbl1##N, acc[mt], 0, 0, 0); \
    _Pragma("unroll")                                                            \
    for (int mt = 0; mt < 4; mt++)                                               \
        acc[mt] = __builtin_amdgcn_mfma_f32_16x16x32_f16(al[mt][0], cbh0##N, acc[mt], 0, 0, 0); \
    _Pragma("unroll")                                                            \
    for (int mt = 0; mt < 4; mt++)                                               \
        acc[mt] = __builtin_amdgcn_mfma_f32_16x16x32_f16(al[mt][1], cbh1##N, acc[mt], 0, 0, 0);

#define EPI_BOTH(N, NTL)                                                         \
    {                                                                            \
        float jt = 0.0f, jb = 0.0f;                                              \
        _Pragma("unroll")                                                        \
        for (int mt = 0; mt < 4; mt++)                                           \
            _Pragma("unroll")                                                    \
            for (int rr = 0; rr < 4; rr++) {                                     \
                float d2 = fmaf(-2.0f, acc[mt][rr], sqi[mt][rr] + sqj##N);       \
                d2 = fmaxf(d2, 0.0f);                                            \
                float dist = __builtin_amdgcn_sqrtf(d2);                         \
                float e2 = __builtin_amdgcn_exp2f(fmaf(c1, dist, SHIFT));        \
                float e2t = (yj##N == ((ypack[mt] >> (8 * rr)) & 255)) ? e2 : 0.0f; \
                ts[mt][rr] += e2t;                                               \
                bs[mt][rr] += e2;                                                \
                jt += e2t;                                                       \
                jb += e2;                                                        \
            }                                                                    \
        s_j[wv][kq][(NTL) * 16 + mrow] = (f32x2){jt, jb};  /* no shuffles */     \
    }

#define EPI_DIAG(N, NTL)                                                         \
    {                                                                            \
        _Pragma("unroll")                                                        \
        for (int mt = 0; mt < 4; mt++)                                           \
            _Pragma("unroll")                                                    \
            for (int rr = 0; rr < 4; rr++) {                                     \
                int i = iw + mt * 16 + kq * 4 + rr;                              \
                float d2 = fmaf(-2.0f, acc[mt][rr], sqi[mt][rr] + sqj##N);       \
                d2 = fmaxf(d2, 0.0f);                                            \
                float dist = __builtin_amdgcn_sqrtf(d2);                         \
                float e2 = __builtin_amdgcn_exp2f(fmaf(c1, dist, SHIFT));        \
                bool offd = (i != jr##N);                                        \
                bool same = offd && (yj##N == ((ypack[mt] >> (8 * rr)) & 255));  \
                bs[mt][rr] += offd ? e2 : 0.0f;                                  \
                ts[mt][rr] += same ? e2 : 0.0f;                                  \
            }                                                                    \
    }

    int ntl = 0;
    // ---- both-sided chunks, 2-wide + remainder ----
    for (; ntl + 2 <= ndch; ntl += 2) {
        DECL_LOAD(0, ntl)
        DECL_LOAD(1, ntl + 1)
        DO_MFMA(0) EPI_BOTH(0, ntl)
        DO_MFMA(1) EPI_BOTH(1, ntl + 1)
    }
    for (; ntl < ndch; ntl++) {
        DECL_LOAD(0, ntl)
        DO_MFMA(0) EPI_BOTH(0, ntl)
    }
    // ---- diagonal chunks, 2-wide + remainder ----
    for (; ntl + 2 <= len; ntl += 2) {
        DECL_LOAD(0, ntl)
        DECL_LOAD(1, ntl + 1)
        DO_MFMA(0) EPI_DIAG(0, ntl)
        DO_MFMA(1) EPI_DIAG(1, ntl + 1)
    }
    for (; ntl < len; ntl++) {
        DECL_LOAD(0, ntl)
        DO_MFMA(0) EPI_DIAG(0, ntl)
    }
#undef DECL_LOAD
#undef DO_MFMA
#undef EPI_BOTH
#undef EPI_DIAG

    // row-side: reduce across the 16 mrow lanes sharing each row, one atomic/row
    #pragma unroll
    for (int mt = 0; mt < 4; mt++)
        #pragma unroll
        for (int rr = 0; rr < 4; rr++) {
            float tv = ts[mt][rr], bv = bs[mt][rr];
            #pragma unroll
            for (int off = 1; off < 16; off <<= 1) {
                tv += __shfl_xor(tv, off, 64);
                bv += __shfl_xor(bv, off, 64);
            }
            if (mrow == 0) {
                int i = iw + mt * 16 + kq * 4 + rr;
                atomicAdd(&top[i], tv);
                atomicAdd(&bot[i], bv);
            }
        }

    // col-side drain: reduce the 16 (wave,kq) float2 slices, one atomic/column
    if (ndch > 0) {
        __syncthreads();
        for (int t = tid; t < ndch * 16; t += 256) {
            float tt = 0.0f, bb = 0.0f;
            #pragma unroll
            for (int v = 0; v < 4; v++)
                #pragma unroll
                for (int q = 0; q < 4; q++) {
                    f32x2 s = s_j[v][q][t];
                    tt += s[0];
                    bb += s[1];
                }
            atomicAdd(&top[c0 * 16 + t], tt);
            atomicAdd(&bot[c0 * 16 + t], bb);
        }
    }

    // fused finalization: last block to finish computes the loss
    __threadfence();
    __syncthreads();
    if (tid == 0) s_last = (atomicAdd(&g_ctr, 1u) == TB - 1);
    __syncthreads();
    if (s_last) {
        float acc2 = 0.0f;
        for (int r2 = tid; r2 < N_ROWS; r2 += 256) {
            float t = __hip_atomic_load(&top[r2], __ATOMIC_RELAXED, __HIP_MEMORY_SCOPE_AGENT);
            float b = __hip_atomic_load(&bot[r2], __ATOMIC_RELAXED, __HIP_MEMORY_SCOPE_AGENT);
            acc2 += (logf(t) - SHIFT_LN) - logf(b * 0x1p-64f + EPS);
        }
        #pragma unroll
        for (int off = 32; off > 0; off >>= 1) acc2 += __shfl_xor(acc2, off, 64);
        if ((tid & 63) == 0) s_red[tid >> 6] = acc2;
        __syncthreads();
        if (tid == 0)
            out[0] = -(s_red[0] + s_red[1] + s_red[2] + s_red[3]) / (float)N_ROWS;
    }
}

extern "C" void kernel_launch(void* const* d_in, const int* in_sizes, int n_in,
                              void* d_out, int out_size, void* d_ws, size_t ws_size,
                              hipStream_t stream) {
    const float* x = (const float*)d_in[0];
    const int*   y = (const int*)d_in[1];
    const float* w = (const float*)d_in[2];
    float* out = (float*)d_out;

    float* ws  = (float*)d_ws;
    float* top = ws;
    float* bot = ws + N_ROWS;
    float* sq  = ws + 2 * N_ROWS;
    _Float16* xh = (_Float16*)(ws + 3 * N_ROWS);
    _Float16* xl = xh + (size_t)N_ROWS * DIM;

    snn_prep<<<N_ROWS / 8, 256, 0, stream>>>(x, xh, xl, sq, top, bot, out);
    snn_mfma<<<TB, 256, 0, stream>>>(xh, xl, sq, y, w, top, bot, out);
}

// Round 15
// 94.748 us; speedup vs baseline: 1.3193x; 1.3193x over previous
//
#include <hip/hip_runtime.h>

typedef _Float16 f16x8 __attribute__((ext_vector_type(8)));
typedef _Float16 f16x2 __attribute__((ext_vector_type(2)));
typedef float    f32x4 __attribute__((ext_vector_type(4)));
typedef float    f32x2 __attribute__((ext_vector_type(2)));

#define N_ROWS 8192
#define DIM 64
#define EPS 1e-8f
#define LOG2E 1.4426950408889634f
#define SHIFT 64.0f                      // exp terms scaled by 2^64
#define SHIFT_LN 44.361419555836499802f  // 64 * ln(2)
#define TILE_I 256                       // i-panel (4 waves x 64 rows, mt=4)
#define NBI (N_ROWS / TILE_I)            // 32 panels
#define TB 512                           // EXACTLY one block per CU slot
#define MAXC 17                          // max j-chunks (16 rows each) per block

// ws: top[8192] | bot[8192] | sq[8192] (f32) | xh[8192*64] | xl[8192*64] (f16)

// fused prep: zero top/bot/out + f16 split + row norms.
// G13: float2 loads (8B/lane), packed f16x2 stores; 2 rows per wave.
__global__ void snn_prep(const float* __restrict__ x, _Float16* __restrict__ xh,
                         _Float16* __restrict__ xl, float* __restrict__ sq,
                         float* __restrict__ top, float* __restrict__ bot,
                         float* __restrict__ out) {
    const int gt = blockIdx.x * 256 + threadIdx.x;
    if (gt < N_ROWS) { top[gt] = 0.0f; bot[gt] = 0.0f; }
    if (gt == 0) out[0] = 0.0f;
    const int lane = threadIdx.x & 63;
    const int row = gt >> 5;                 // 2 rows per wave
    const int cp  = (lane & 31) * 2;         // this lane's column pair
    f32x2 v = *(const f32x2*)(x + row * DIM + cp);
    _Float16 h0 = (_Float16)v[0], h1 = (_Float16)v[1];
    _Float16 l0 = (_Float16)(v[0] - (float)h0);
    _Float16 l1 = (_Float16)(v[1] - (float)h1);
    *(f16x2*)(xh + row * DIM + cp) = (f16x2){h0, h1};
    *(f16x2*)(xl + row * DIM + cp) = (f16x2){l0, l1};
    float s = v[0] * v[0] + v[1] * v[1];
    #pragma unroll
    for (int off = 16; off > 0; off >>= 1) s += __shfl_xor(s, off, 64);
    if ((lane & 31) == 0) sq[row] = s;
}

// Symmetric triangular pass — R13 kernel VERBATIM (best measured: mfma ~38us,
// total 94.26us). R14 post-mortem: fusing the finalization via per-block
// __threadfence + device atomic counter cost ~30us (device-scope fence with
// 8 non-coherent per-XCD L2s, paid in EVERY block's epilogue) -> reverted to
// the separate snn_final dispatch (2.5us).
// Final map of measured levers on the mfma stall (~25us of its 38):
//  - R8 partition: 512 uniform blocks (16-17 chunks) -> ONE scheduling round
//  - 2-wide iterations: widest body under the empirical 128-VGPR wall
//    (R3/R9/R12: >128 live regs -> spill, never allocates >128)
//  - nulls/negatives: TLP (R10), LDS B-staging (R6), SW prefetch (R3/R5),
//    4-wide (R12 spill), col-shuffle removal (R13 neutral), fused final (R14)
__global__ __launch_bounds__(256, 2) void snn_mfma(
    const _Float16* __restrict__ xh, const _Float16* __restrict__ xl,
    const float* __restrict__ sq, const int* __restrict__ y,
    const float* __restrict__ w,
    float* __restrict__ top, float* __restrict__ bot)
{
    __shared__ float s_sqj[MAXC * 16];
    __shared__ int   s_yj[MAXC * 16];
    __shared__ f32x2 s_j[4][4][MAXC * 16];   // [wave][kq][col] {top,bot} partials

    // ---- decode bid -> (panel bi, chunk range [c0, c0+len)) — R8 verbatim ----
    const int bid = blockIdx.x;
    int bi = 0, kk = 0, cum = 0;
    for (int p = 0; p < NBI; p++) {
        int nb = (p < 16) ? p + 1 : p;          // blocks in panel p
        if (bid < cum + nb) { bi = p; kk = bid - cum; break; }
        cum += nb;
    }
    int c0, len;
    if (bi < 16)      { c0 = 16 * kk;              len = 16; }
    else if (kk < 16) { c0 = 17 * kk;              len = 17; }
    else              { c0 = 272 + 16 * (kk - 16); len = 16; }
    const int ndch = min(max(16 * bi - c0, 0), len);  // leading non-diag chunks
    const int I0 = bi * TILE_I;

    const int tid = threadIdx.x, wv = tid >> 6, lane = tid & 63;
    const int mrow = lane & 15, kq = lane >> 4;

    for (int t = tid; t < len * 16; t += 256) {
        s_sqj[t] = sq[c0 * 16 + t];
        s_yj[t]  = y[c0 * 16 + t];
    }
    __syncthreads();

    const int iw = I0 + wv * 64;   // this wave's first i-row

    // A fragments resident for the block lifetime (64 VGPRs)
    f16x8 ah[4][2], al[4][2];
    #pragma unroll
    for (int mt = 0; mt < 4; mt++)
        #pragma unroll
        for (int kc = 0; kc < 2; kc++) {
            int a = (iw + mt * 16 + mrow) * DIM + kc * 32 + kq * 8;
            ah[mt][kc] = *(const f16x8*)(xh + a);
            al[mt][kc] = *(const f16x8*)(xl + a);
        }

    // per-slot row metadata: i = iw + mt*16 + kq*4 + rr ; labels packed 4/VGPR
    float sqi[4][4]; int ypack[4];
    #pragma unroll
    for (int mt = 0; mt < 4; mt++) {
        int yp = 0;
        #pragma unroll
        for (int rr = 0; rr < 4; rr++) {
            int i = iw + mt * 16 + kq * 4 + rr;
            sqi[mt][rr] = sq[i];
            yp |= (y[i] & 255) << (8 * rr);
        }
        ypack[mt] = yp;
    }

    float ts[4][4], bs[4][4];
    #pragma unroll
    for (int mt = 0; mt < 4; mt++)
        #pragma unroll
        for (int rr = 0; rr < 4; rr++) { ts[mt][rr] = 0.0f; bs[mt][rr] = 0.0f; }

    const float c1 = -w[0] * LOG2E;
    f32x4 acc[4];

// declare + issue loads for one chunk (suffix N), chunk index NTL
#define DECL_LOAD(N, NTL)                                                        \
    const int jr##N = (c0 + (NTL)) * 16 + mrow;                                  \
    const int boff##N = jr##N * DIM + kq * 8;                                    \
    f16x8 cbh0##N = *(const f16x8*)(xh + boff##N);                               \
    f16x8 cbh1##N = *(const f16x8*)(xh + boff##N + 32);                          \
    f16x8 cbl0##N = *(const f16x8*)(xl + boff##N);                               \
    f16x8 cbl1##N = *(const f16x8*)(xl + boff##N + 32);                          \
    const float sqj##N = s_sqj[(NTL) * 16 + mrow];                               \
    const int   yj##N  = s_yj[(NTL) * 16 + mrow];

#define DO_MFMA(N)                                                               \
    _Pragma("unroll")                                                            \
    for (int mt = 0; mt < 4; mt++) acc[mt] = (f32x4){0.f, 0.f, 0.f, 0.f};        \
    _Pragma("unroll")                                                            \
    for (int mt = 0; mt < 4; mt++)                                               \
        acc[mt] = __builtin_amdgcn_mfma_f32_16x16x32_f16(ah[mt][0], cbh0##N, acc[mt], 0, 0, 0); \
    _Pragma("unroll")                                                            \
    for (int mt = 0; mt < 4; mt++)                                               \
        acc[mt] = __builtin_amdgcn_mfma_f32_16x16x32_f16(ah[mt][1], cbh1##N, acc[mt], 0, 0, 0); \
    _Pragma("unroll")                                                            \
    for (int mt = 0; mt < 4; mt++)                                               \
        acc[mt] = __builtin_amdgcn_mfma_f32_16x16x32_f16(ah[mt][0], cbl0##N, acc[mt], 0, 0, 0); \
    _Pragma("unroll")                                                            \
    for (int mt = 0; mt < 4; mt++)                                               \
        acc[mt] = __builtin_amdgcn_mfma_f32_16x16x32_f16(ah[mt][1], cbl1##N, acc[mt], 0, 0, 0); \
    _Pragma("unroll")                                                            \
    for (int mt = 0; mt < 4; mt++)                                               \
        acc[mt] = __builtin_amdgcn_mfma_f32_16x16x32_f16(al[mt][0], cbh0##N, acc[mt], 0, 0, 0); \
    _Pragma("unroll")                                                            \
    for (int mt = 0; mt < 4; mt++)                                               \
        acc[mt] = __builtin_amdgcn_mfma_f32_16x16x32_f16(al[mt][1], cbh1##N, acc[mt], 0, 0, 0);

#define EPI_BOTH(N, NTL)                                                         \
    {                                                                            \
        float jt = 0.0f, jb = 0.0f;                                              \
        _Pragma("unroll")                                                        \
        for (int mt = 0; mt < 4; mt++)                                           \
            _Pragma("unroll")                                                    \
            for (int rr = 0; rr < 4; rr++) {                                     \
                float d2 = fmaf(-2.0f, acc[mt][rr], sqi[mt][rr] + sqj##N);       \
                d2 = fmaxf(d2, 0.0f);                                            \
                float dist = __builtin_amdgcn_sqrtf(d2);                         \
                float e2 = __builtin_amdgcn_exp2f(fmaf(c1, dist, SHIFT));        \
                float e2t = (yj##N == ((ypack[mt] >> (8 * rr)) & 255)) ? e2 : 0.0f; \
                ts[mt][rr] += e2t;                                               \
                bs[mt][rr] += e2;                                                \
                jt += e2t;                                                       \
                jb += e2;                                                        \
            }                                                                    \
        s_j[wv][kq][(NTL) * 16 + mrow] = (f32x2){jt, jb};  /* no shuffles */     \
    }

#define EPI_DIAG(N, NTL)                                                         \
    {                                                                            \
        _Pragma("unroll")                                                        \
        for (int mt = 0; mt < 4; mt++)                                           \
            _Pragma("unroll")                                                    \
            for (int rr = 0; rr < 4; rr++) {                                     \
                int i = iw + mt * 16 + kq * 4 + rr;                              \
                float d2 = fmaf(-2.0f, acc[mt][rr], sqi[mt][rr] + sqj##N);       \
                d2 = fmaxf(d2, 0.0f);                                            \
                float dist = __builtin_amdgcn_sqrtf(d2);                         \
                float e2 = __builtin_amdgcn_exp2f(fmaf(c1, dist, SHIFT));        \
                bool offd = (i != jr##N);                                        \
                bool same = offd && (yj##N == ((ypack[mt] >> (8 * rr)) & 255));  \
                bs[mt][rr] += offd ? e2 : 0.0f;                                  \
                ts[mt][rr] += same ? e2 : 0.0f;                                  \
            }                                                                    \
    }

    int ntl = 0;
    // ---- both-sided chunks, 2-wide + remainder ----
    for (; ntl + 2 <= ndch; ntl += 2) {
        DECL_LOAD(0, ntl)
        DECL_LOAD(1, ntl + 1)
        DO_MFMA(0) EPI_BOTH(0, ntl)
        DO_MFMA(1) EPI_BOTH(1, ntl + 1)
    }
    for (; ntl < ndch; ntl++) {
        DECL_LOAD(0, ntl)
        DO_MFMA(0) EPI_BOTH(0, ntl)
    }
    // ---- diagonal chunks, 2-wide + remainder ----
    for (; ntl + 2 <= len; ntl += 2) {
        DECL_LOAD(0, ntl)
        DECL_LOAD(1, ntl + 1)
        DO_MFMA(0) EPI_DIAG(0, ntl)
        DO_MFMA(1) EPI_DIAG(1, ntl + 1)
    }
    for (; ntl < len; ntl++) {
        DECL_LOAD(0, ntl)
        DO_MFMA(0) EPI_DIAG(0, ntl)
    }
#undef DECL_LOAD
#undef DO_MFMA
#undef EPI_BOTH
#undef EPI_DIAG

    // row-side: reduce across the 16 mrow lanes sharing each row, one atomic/row
    #pragma unroll
    for (int mt = 0; mt < 4; mt++)
        #pragma unroll
        for (int rr = 0; rr < 4; rr++) {
            float tv = ts[mt][rr], bv = bs[mt][rr];
            #pragma unroll
            for (int off = 1; off < 16; off <<= 1) {
                tv += __shfl_xor(tv, off, 64);
                bv += __shfl_xor(bv, off, 64);
            }
            if (mrow == 0) {
                int i = iw + mt * 16 + kq * 4 + rr;
                atomicAdd(&top[i], tv);
                atomicAdd(&bot[i], bv);
            }
        }

    // col-side drain: reduce the 16 (wave,kq) float2 slices, one atomic/column
    if (ndch > 0) {
        __syncthreads();
        for (int t = tid; t < ndch * 16; t += 256) {
            float tt = 0.0f, bb = 0.0f;
            #pragma unroll
            for (int v = 0; v < 4; v++)
                #pragma unroll
                for (int q = 0; q < 4; q++) {
                    f32x2 s = s_j[v][q][t];
                    tt += s[0];
                    bb += s[1];
                }
            atomicAdd(&top[c0 * 16 + t], tt);
            atomicAdd(&bot[c0 * 16 + t], bb);
        }
    }
}

__global__ __launch_bounds__(256) void snn_final(
    const float* __restrict__ top, const float* __restrict__ bot,
    float* __restrict__ out)
{
    const int i = blockIdx.x * 256 + threadIdx.x;
    float t = top[i];                    // top * 2^64, normal fp32
    float b = bot[i] * 0x1p-64f + EPS;   // bot tiny; +eps dominates
    float acc = (logf(t) - SHIFT_LN) - logf(b);
    #pragma unroll
    for (int off = 32; off > 0; off >>= 1) acc += __shfl_xor(acc, off, 64);
    __shared__ float red[4];
    if ((threadIdx.x & 63) == 0) red[threadIdx.x >> 6] = acc;
    __syncthreads();
    if (threadIdx.x == 0) {
        float s = red[0] + red[1] + red[2] + red[3];
        atomicAdd(out, -s / (float)N_ROWS);
    }
}

extern "C" void kernel_launch(void* const* d_in, const int* in_sizes, int n_in,
                              void* d_out, int out_size, void* d_ws, size_t ws_size,
                              hipStream_t stream) {
    const float* x = (const float*)d_in[0];
    const int*   y = (const int*)d_in[1];
    const float* w = (const float*)d_in[2];
    float* out = (float*)d_out;

    float* ws  = (float*)d_ws;
    float* top = ws;
    float* bot = ws + N_ROWS;
    float* sq  = ws + 2 * N_ROWS;
    _Float16* xh = (_Float16*)(ws + 3 * N_ROWS);
    _Float16* xl = xh + (size_t)N_ROWS * DIM;

    snn_prep<<<N_ROWS / 8, 256, 0, stream>>>(x, xh, xl, sq, top, bot, out);
    snn_mfma<<<TB, 256, 0, stream>>>(xh, xl, sq, y, w, top, bot);
    snn_final<<<N_ROWS / 256, 256, 0, stream>>>(top, bot, out);
}